// Round 22
// baseline (241.214 us; speedup 1.0000x reference)
//
#include <hip/hip_runtime.h>
#include <hip/hip_bf16.h>

typedef __attribute__((ext_vector_type(8))) short short8;
typedef __attribute__((ext_vector_type(4))) short short4v;
typedef __attribute__((ext_vector_type(4))) float f32x4;
typedef __attribute__((ext_vector_type(2))) float f32x2;

__device__ __forceinline__ unsigned short f2bf(float f) {
    unsigned int u = __builtin_bit_cast(unsigned int, f);
    u += 0x7fffu + ((u >> 16) & 1u);   // round-to-nearest-even
    return (unsigned short)(u >> 16);
}
__device__ __forceinline__ unsigned int pack2(float a, float b) {
    union { __hip_bfloat162 h; unsigned int u; } r;
    r.h = __float22bfloat162_rn(make_float2(a, b));
    return r.u;
}
__device__ __forceinline__ short4v cvt4(float a, float b, float c, float d) {
    union { __hip_bfloat162 h[2]; short4v s; } u;
    u.h[0] = __float22bfloat162_rn(make_float2(a, b));
    u.h[1] = __float22bfloat162_rn(make_float2(c, d));
    return u.s;
}

// ---------------------------------------------------------------------------
// Kernel A: partial adjacency sums over 60-frame chunks. grid (5,32).
// ---------------------------------------------------------------------------
__global__ void kA(const float* __restrict__ xx, float* __restrict__ At_part) {
    __shared__ float xs3[3][60][25];
    const int tc = blockIdx.x, n = blockIdx.y;
    const int tid = threadIdx.x;
    const float* base = xx + (size_t)n * 22500 + tc * 1500;
    for (int idx = tid; idx < 4500; idx += 256) {
        int ch = idx / 1500, rt = idx % 1500;
        xs3[ch][rt / 25][rt % 25] = base[ch * 7500 + rt];
    }
    __syncthreads();
    for (int p = tid; p < 625; p += 256) {
        int v = p / 25, u = p % 25;
        float s = 0.f;
        for (int t = 0; t < 60; ++t) {
            float dx = xs3[0][t][v] - xs3[0][t][u];
            float dy = xs3[1][t][v] - xs3[1][t][u];
            float dz = xs3[2][t][v] - xs3[2][t][u];
            s += __expf(-2.f * (dx * dx + dy * dy + dz * dz));
        }
        At_part[(size_t)(n * 5 + tc) * 625 + p] = s;
    }
}

// ---------------------------------------------------------------------------
// Kernel B1: per-sample reduce + symmetric normalization. grid 32.
// ---------------------------------------------------------------------------
__global__ void kB1(const float* __restrict__ At_part, float* __restrict__ Acontrib) {
    __shared__ float At[625];
    __shared__ float dinv[25];
    const int n = blockIdx.x, tid = threadIdx.x;
    for (int p = tid; p < 625; p += 256) {
        float s = 0.f;
        for (int tc = 0; tc < 5; ++tc) s += At_part[(size_t)(n * 5 + tc) * 625 + p];
        At[p] = s;
    }
    __syncthreads();
    if (tid < 25) {
        float d = 0.f;
        for (int u = 0; u < 25; ++u) d += At[tid * 25 + u];
        dinv[tid] = rsqrtf(d * (1.f / 300.f));
    }
    __syncthreads();
    for (int p = tid; p < 625; p += 256)
        Acontrib[n * 625 + p] = At[p] * (1.f / 300.f) * dinv[p / 25] * dinv[p % 25] * (1.f / 32.f);
}

// ---------------------------------------------------------------------------
// Kernel B2: block 0 -> bsTg (bf16 [64][72], zero-padded) + fused bias;
//            blocks 1..36 -> W'' = W * bn_scale  (layout [o][k], row-major).
// ---------------------------------------------------------------------------
__global__ void kB2(const float* __restrict__ Acontrib, const float* __restrict__ A_res,
                    const float* __restrict__ W, const float* __restrict__ b,
                    const float* __restrict__ gamma, const float* __restrict__ beta,
                    const float* __restrict__ rm, const float* __restrict__ rv,
                    short* __restrict__ bsTg, short* __restrict__ Wpg,
                    float* __restrict__ bbg) {
    const int tid = threadIdx.x;
    if (blockIdx.x == 0) {
        __shared__ float macc[625];
        for (int p = tid; p < 625; p += 256) {
            float s = 0.f;
            for (int n = 0; n < 32; ++n) s += Acontrib[n * 625 + p];
            macc[p] = s;
        }
        __syncthreads();
        for (int idx = tid; idx < 64 * 72; idx += 256) {
            int col = idx / 72, u = idx % 72;
            float v = 0.f;
            if (col < 50 && u < 50) v = macc[(col % 25) * 25 + (u % 25)] + A_res[col * 50 + u];
            bsTg[idx] = (short)f2bf(v);
        }
        if (tid < 192) {
            float sc = gamma[tid] * rsqrtf(rv[tid] + 1e-5f);
            bbg[tid] = b[tid] * sc + beta[tid] - rm[tid] * sc;
        }
    } else {
        const int e = (blockIdx.x - 1) * 1024 + tid * 4;
        const int o = e / 192;
        const float sc = gamma[o] * rsqrtf(rv[o] + 1e-5f);
        float4 w = *(const float4*)(W + e);
        short4v s4 = { (short)f2bf(w.x * sc), (short)f2bf(w.y * sc),
                       (short)f2bf(w.z * sc), (short)f2bf(w.w * sc) };
        *(short4v*)(Wpg + e) = s4;
    }
}

// ---------------------------------------------------------------------------
// Fused kernel kCf: graph-conv + 1x1 conv + BN + ReLU, no intermediate.
// grid (15,32)=480 blocks, 384 thr = 6 waves, TC=20 t/block, ONE
// lgkm+barrier per t (R20 structure).  vs R21: store banking deepened to
// FOUR timesteps -- bank tl%4 in {0,1,2} (st[2][3][8], +48 VGPR), write each
// (n,o) row's 400B span in one burst at tl%4==3 (halves boundary-sector
// write amplification again).
// ---------------------------------------------------------------------------
#define TCF 20
__global__ __launch_bounds__(384, 3)
void kCf(const float* __restrict__ x, const short* __restrict__ Wpg,
         const short* __restrict__ bsTg, const float* __restrict__ bbg,
         float* __restrict__ out) {
    __shared__ __align__(16) char xsb[2 * 12288];
    __shared__ __align__(16) short bsT[64 * 72];
    __shared__ __align__(16) short a2T[2][32][208];

    const int tid = threadIdx.x;
    const int lane = tid & 63;
    const int wid = tid >> 6;          // 0..5
    const int lam = lane & 15;
    const int kc = (lane >> 4) * 8;
    const int cb = (lane >> 4) * 4;
    const int n = blockIdx.y;
    const int t0 = blockIdx.x * TCF;
    const int gb0 = n * 1440000 + t0 * 50;
    const int cgl = wid * 16 + lam;

    // ---- t-invariant per-thread stage offsets ----
    int goff[7], loff[7];
#pragma unroll
    for (int i = 0; i < 7; ++i) {
        int idx = i * 384 + tid;
        int idc = idx < 2400 ? idx : 2399;
        int c = idc / 25, q = idc - c * 25;
        goff[i] = c * 15000 + 2 * q;
        loff[i] = (c * 128 + q * 4) ^ ((c & 7) << 4);
    }

    // W'' fragments in regs (GEMM2 B-operand) + bias
    short8 wf[2][6];
#pragma unroll
    for (int ot = 0; ot < 2; ++ot)
#pragma unroll
        for (int ks = 0; ks < 6; ++ks)
            wf[ot][ks] = *(const short8*)(Wpg + ((2 * wid + ot) * 16 + lam) * 192 + ks * 32 + kc);
    float bb[2];
#pragma unroll
    for (int ot = 0; ot < 2; ++ot) bb[ot] = bbg[(2 * wid + ot) * 16 + lam];

    // ---- prologue ----
    f32x2 pf2[13];
#pragma unroll
    for (int i = 0; i < 13; ++i) {
        int idx = i * 384 + tid;
        idx = idx < 4800 ? idx : 4799;
        int c = idx / 50, q2 = idx - c * 50;
        int tl = q2 >= 25, q = q2 - 25 * tl;
        pf2[i] = *(const f32x2*)(x + gb0 + c * 15000 + tl * 50 + 2 * q);
    }
    {
        const int4* src = (const int4*)bsTg;
        int4* dst = (int4*)bsT;
        for (int i = tid; i < 576; i += 384) dst[i] = src[i];
    }
    // zero xsb u-pads (both slots)
    for (int idx = tid; idx < 1344; idx += 384) {
        int r = idx / 7, k = idx - r * 7;
        int slot = r / 96, c = r - 96 * slot;
        *(unsigned int*)(xsb + ((slot * 12288 + c * 128 + (50 + 2 * k) * 2) ^ ((c & 7) << 4))) = 0;
    }
    // zero a2T pad rows 25..31 (both buffers)
    for (int idx = tid; idx < 1456; idx += 384) {
        int buf = idx / 728, rem = idx - buf * 728;
        int row = 25 + rem / 104, col2 = rem - (rem / 104) * 104;
        *((unsigned int*)&a2T[buf][row][0] + col2) = 0;
    }
    // write t0 -> slot0, t1 -> slot1
#pragma unroll
    for (int i = 0; i < 13; ++i) {
        int idx = i * 384 + tid;
        if (idx < 4800) {
            int c = idx / 50, q2 = idx - c * 50;
            int tl = q2 >= 25, q = q2 - 25 * tl;
            *(unsigned int*)(xsb + ((tl * 12288 + c * 128 + q * 4) ^ ((c & 7) << 4)))
                = pack2(pf2[i].x, pf2[i].y);
        }
    }
    asm volatile("s_waitcnt lgkmcnt(0)" ::: "memory");
    __builtin_amdgcn_s_barrier();

    const f32x4 z = {0.f, 0.f, 0.f, 0.f};
    f32x2 pf[7];
    float st[2][3][8];                  // banked epilogue values (3 phases)

#pragma unroll 1
    for (int tl = 0; tl < TCF; ++tl) {
        const int slot = tl & 1;
        short* a2w = &a2T[slot][0][0];

        // issue t+2 coalesced loads early (precomputed addresses)
        if (tl < TCF - 2) {
            const float* xb2 = x + gb0 + (tl + 2) * 50;
#pragma unroll
            for (int i = 0; i < 7; ++i)
                if (i < 6 || tid < 96) pf[i] = *(const f32x2*)(xb2 + goff[i]);
        }

        // ---- GEMM1: D[v][c] (8 MFMA) ----
        short8 xb[2];
#pragma unroll
        for (int ks = 0; ks < 2; ++ks)
            xb[ks] = *(const short8*)(xsb +
                ((slot * 12288 + cgl * 128 + (ks * 32 + kc) * 2) ^ ((cgl & 7) << 4)));
        f32x4 acc1[4];
#pragma unroll
        for (int m = 0; m < 4; ++m) acc1[m] = z;
#pragma unroll
        for (int ks = 0; ks < 2; ++ks)
#pragma unroll
            for (int m = 0; m < 4; ++m) {
                const short8 af = *(const short8*)(bsT + (m * 16 + lam) * 72 + ks * 32 + kc);
                acc1[m] = __builtin_amdgcn_mfma_f32_16x16x32_bf16(af, xb[ks], acc1[m], 0, 0, 0);
            }

        // scatter agg -> a2T[slot][vs][s*96 + c]
#pragma unroll
        for (int m = 0; m < 3; ++m) {
            short4v sv = cvt4(acc1[m][0], acc1[m][1], acc1[m][2], acc1[m][3]);
#pragma unroll
            for (int r = 0; r < 4; ++r) {
                const int v = m * 16 + cb + r;
                const int s = v >= 25;
                a2w[(v - 25 * s) * 208 + s * 96 + cgl] = sv[r];
            }
        }
        if (cb == 0) {
            a2w[23 * 208 + 96 + cgl] = (short)f2bf(acc1[3][0]);
            a2w[24 * 208 + 96 + cgl] = (short)f2bf(acc1[3][1]);
        }
        asm volatile("s_waitcnt lgkmcnt(0)" ::: "memory");
        __builtin_amdgcn_s_barrier();   // a2T[slot] ready; all xb reads done

        // ---- GEMM2 (flipped): D[tv][o], W'' from registers (24 MFMA) ----
        f32x4 acc2[2][2];
#pragma unroll
        for (int g = 0; g < 2; ++g) { acc2[g][0] = z; acc2[g][1] = z; }
#pragma unroll
        for (int ks = 0; ks < 6; ++ks) {
            const short8 A0 = *(const short8*)(a2w + lam * 208 + ks * 32 + kc);
            const short8 A1 = *(const short8*)(a2w + (16 + lam) * 208 + ks * 32 + kc);
#pragma unroll
            for (int ot = 0; ot < 2; ++ot) {
                acc2[0][ot] = __builtin_amdgcn_mfma_f32_16x16x32_bf16(A0, wf[ot][ks], acc2[0][ot], 0, 0, 0);
                acc2[1][ot] = __builtin_amdgcn_mfma_f32_16x16x32_bf16(A1, wf[ot][ks], acc2[1][ot], 0, 0, 0);
            }
        }

        // ---- epilogue: bank 3 phases, store 4 regions per row at ph==3 ----
        const int ph = tl & 3;
        if (ph < 3) {
#pragma unroll
            for (int ot = 0; ot < 2; ++ot) {
#pragma unroll
                for (int r = 0; r < 4; ++r) {
                    float vv = acc2[0][ot][r] + bb[ot];
                    st[ot][ph][r] = vv > 0.f ? vv : 0.f;
                }
#pragma unroll
                for (int r = 0; r < 4; ++r) {
                    float vv = acc2[1][ot][r] + bb[ot];
                    st[ot][ph][4 + r] = vv > 0.f ? vv : 0.f;
                }
            }
        } else {
            const int t = t0 + tl;
#pragma unroll
            for (int ot = 0; ot < 2; ++ot) {
                const int o = (2 * wid + ot) * 16 + lam;
                float* op0 = out + ((size_t)(n * 192 + o) * 300 + (t - 3)) * 25;
                // banked regions t-3, t-2, t-1
#pragma unroll
                for (int g = 0; g < 3; ++g) {
                    float* opg = op0 + g * 25;
#pragma unroll
                    for (int r = 0; r < 4; ++r) opg[cb + r] = st[ot][g][r];
#pragma unroll
                    for (int r = 0; r < 4; ++r) {
                        const int tv = 16 + cb + r;
                        if (tv < 25) opg[tv] = st[ot][g][4 + r];
                    }
                }
                // current region t
                float* opc = op0 + 75;
#pragma unroll
                for (int r = 0; r < 4; ++r) {
                    float vv = acc2[0][ot][r] + bb[ot];
                    opc[cb + r] = vv > 0.f ? vv : 0.f;
                }
#pragma unroll
                for (int r = 0; r < 4; ++r) {
                    const int tv = 16 + cb + r;
                    if (tv < 25) {
                        float vv = acc2[1][ot][r] + bb[ot];
                        opc[tv] = vv > 0.f ? vv : 0.f;
                    }
                }
            }
        }

        // write t+2 into the freed slot
        if (tl < TCF - 2) {
            char* xw = xsb + slot * 12288;
#pragma unroll
            for (int i = 0; i < 7; ++i)
                if (i < 6 || tid < 96)
                    *(unsigned int*)(xw + loff[i]) = pack2(pf[i].x, pf[i].y);
        }
        // no trailing barrier: double-buffered xsb/a2T; next iter's
        // lgkm(0)+barrier orders these LDS writes before their reads.
    }
}

// ---------------------------------------------------------------------------
extern "C" void kernel_launch(void* const* d_in, const int* in_sizes, int n_in,
                              void* d_out, int out_size, void* d_ws, size_t ws_size,
                              hipStream_t stream) {
    const float* x     = (const float*)d_in[0];
    const float* xx    = (const float*)d_in[1];
    const float* A_res = (const float*)d_in[2];
    const float* W     = (const float*)d_in[3];
    const float* b     = (const float*)d_in[4];
    const float* gamma = (const float*)d_in[5];
    const float* beta  = (const float*)d_in[6];
    const float* rm    = (const float*)d_in[7];
    const float* rv    = (const float*)d_in[8];
    float* out = (float*)d_out;

    char* ws = (char*)d_ws;
    float* At_part  = (float*)ws;                    // 400000 B
    float* Acontrib = (float*)(ws + 400000);         //  80000 B
    short* bsTg     = (short*)(ws + 480000);         //   9216 B
    short* Wpg      = (short*)(ws + 489216);         //  73728 B
    float* bbg      = (float*)(ws + 562944);         //    768 B

    kA<<<dim3(5, 32), 256, 0, stream>>>(xx, At_part);
    kB1<<<32, 256, 0, stream>>>(At_part, Acontrib);
    kB2<<<37, 256, 0, stream>>>(Acontrib, A_res, W, b, gamma, beta, rm, rv, bsTg, Wpg, bbg);
    kCf<<<dim3(15, 32), 384, 0, stream>>>(x, Wpg, bsTg, bbg, out);
}

// Round 23
// 153.634 us; speedup vs baseline: 1.5701x; 1.5701x over previous
//
#include <hip/hip_runtime.h>
#include <hip/hip_bf16.h>

typedef __attribute__((ext_vector_type(8))) short short8;
typedef __attribute__((ext_vector_type(4))) short short4v;
typedef __attribute__((ext_vector_type(4))) float f32x4;
typedef __attribute__((ext_vector_type(2))) float f32x2;

__device__ __forceinline__ unsigned short f2bf(float f) {
    unsigned int u = __builtin_bit_cast(unsigned int, f);
    u += 0x7fffu + ((u >> 16) & 1u);   // round-to-nearest-even
    return (unsigned short)(u >> 16);
}
__device__ __forceinline__ unsigned int pack2(float a, float b) {
    union { __hip_bfloat162 h; unsigned int u; } r;
    r.h = __float22bfloat162_rn(make_float2(a, b));
    return r.u;
}
__device__ __forceinline__ short4v cvt4(float a, float b, float c, float d) {
    union { __hip_bfloat162 h[2]; short4v s; } u;
    u.h[0] = __float22bfloat162_rn(make_float2(a, b));
    u.h[1] = __float22bfloat162_rn(make_float2(c, d));
    return u.s;
}

// ---------------------------------------------------------------------------
// Kernel A: partial adjacency sums over 60-frame chunks. grid (5,32).
// ---------------------------------------------------------------------------
__global__ void kA(const float* __restrict__ xx, float* __restrict__ At_part) {
    __shared__ float xs3[3][60][25];
    const int tc = blockIdx.x, n = blockIdx.y;
    const int tid = threadIdx.x;
    const float* base = xx + (size_t)n * 22500 + tc * 1500;
    for (int idx = tid; idx < 4500; idx += 256) {
        int ch = idx / 1500, rt = idx % 1500;
        xs3[ch][rt / 25][rt % 25] = base[ch * 7500 + rt];
    }
    __syncthreads();
    for (int p = tid; p < 625; p += 256) {
        int v = p / 25, u = p % 25;
        float s = 0.f;
        for (int t = 0; t < 60; ++t) {
            float dx = xs3[0][t][v] - xs3[0][t][u];
            float dy = xs3[1][t][v] - xs3[1][t][u];
            float dz = xs3[2][t][v] - xs3[2][t][u];
            s += __expf(-2.f * (dx * dx + dy * dy + dz * dz));
        }
        At_part[(size_t)(n * 5 + tc) * 625 + p] = s;
    }
}

// ---------------------------------------------------------------------------
// Kernel B1: per-sample reduce + symmetric normalization. grid 32.
// ---------------------------------------------------------------------------
__global__ void kB1(const float* __restrict__ At_part, float* __restrict__ Acontrib) {
    __shared__ float At[625];
    __shared__ float dinv[25];
    const int n = blockIdx.x, tid = threadIdx.x;
    for (int p = tid; p < 625; p += 256) {
        float s = 0.f;
        for (int tc = 0; tc < 5; ++tc) s += At_part[(size_t)(n * 5 + tc) * 625 + p];
        At[p] = s;
    }
    __syncthreads();
    if (tid < 25) {
        float d = 0.f;
        for (int u = 0; u < 25; ++u) d += At[tid * 25 + u];
        dinv[tid] = rsqrtf(d * (1.f / 300.f));
    }
    __syncthreads();
    for (int p = tid; p < 625; p += 256)
        Acontrib[n * 625 + p] = At[p] * (1.f / 300.f) * dinv[p / 25] * dinv[p % 25] * (1.f / 32.f);
}

// ---------------------------------------------------------------------------
// Kernel B2: block 0 -> bsTg (bf16 [64][72], zero-padded) + fused bias;
//            blocks 1..36 -> W'' = W * bn_scale  (layout [o][k], row-major).
// ---------------------------------------------------------------------------
__global__ void kB2(const float* __restrict__ Acontrib, const float* __restrict__ A_res,
                    const float* __restrict__ W, const float* __restrict__ b,
                    const float* __restrict__ gamma, const float* __restrict__ beta,
                    const float* __restrict__ rm, const float* __restrict__ rv,
                    short* __restrict__ bsTg, short* __restrict__ Wpg,
                    float* __restrict__ bbg) {
    const int tid = threadIdx.x;
    if (blockIdx.x == 0) {
        __shared__ float macc[625];
        for (int p = tid; p < 625; p += 256) {
            float s = 0.f;
            for (int n = 0; n < 32; ++n) s += Acontrib[n * 625 + p];
            macc[p] = s;
        }
        __syncthreads();
        for (int idx = tid; idx < 64 * 72; idx += 256) {
            int col = idx / 72, u = idx % 72;
            float v = 0.f;
            if (col < 50 && u < 50) v = macc[(col % 25) * 25 + (u % 25)] + A_res[col * 50 + u];
            bsTg[idx] = (short)f2bf(v);
        }
        if (tid < 192) {
            float sc = gamma[tid] * rsqrtf(rv[tid] + 1e-5f);
            bbg[tid] = b[tid] * sc + beta[tid] - rm[tid] * sc;
        }
    } else {
        const int e = (blockIdx.x - 1) * 1024 + tid * 4;
        const int o = e / 192;
        const float sc = gamma[o] * rsqrtf(rv[o] + 1e-5f);
        float4 w = *(const float4*)(W + e);
        short4v s4 = { (short)f2bf(w.x * sc), (short)f2bf(w.y * sc),
                       (short)f2bf(w.z * sc), (short)f2bf(w.w * sc) };
        *(short4v*)(Wpg + e) = s4;
    }
}

// ---------------------------------------------------------------------------
// Fused kernel kCf (== R21, best measured 154.0 us): graph-conv + 1x1 conv
// + BN + ReLU, no intermediate.  grid (15,32)=480 blocks, 384 thr = 6 waves,
// TC=20 t/block, ONE lgkm+barrier per t.  Deferred PAIRED stores (depth 2:
// st[2][8], +16 VGPR -- depth 4 spills, R22): even-t epilogue banked in
// registers, written together with odd-t's 100B region so each (n,o) row
// gets 200B back-to-back (L2 sector merge).
// ---------------------------------------------------------------------------
#define TCF 20
__global__ __launch_bounds__(384, 3)
void kCf(const float* __restrict__ x, const short* __restrict__ Wpg,
         const short* __restrict__ bsTg, const float* __restrict__ bbg,
         float* __restrict__ out) {
    __shared__ __align__(16) char xsb[2 * 12288];
    __shared__ __align__(16) short bsT[64 * 72];
    __shared__ __align__(16) short a2T[2][32][208];

    const int tid = threadIdx.x;
    const int lane = tid & 63;
    const int wid = tid >> 6;          // 0..5
    const int lam = lane & 15;
    const int kc = (lane >> 4) * 8;
    const int cb = (lane >> 4) * 4;
    const int n = blockIdx.y;
    const int t0 = blockIdx.x * TCF;
    const int gb0 = n * 1440000 + t0 * 50;
    const int cgl = wid * 16 + lam;

    // ---- t-invariant per-thread stage offsets ----
    int goff[7], loff[7];
#pragma unroll
    for (int i = 0; i < 7; ++i) {
        int idx = i * 384 + tid;
        int idc = idx < 2400 ? idx : 2399;
        int c = idc / 25, q = idc - c * 25;
        goff[i] = c * 15000 + 2 * q;
        loff[i] = (c * 128 + q * 4) ^ ((c & 7) << 4);
    }

    // W'' fragments in regs (GEMM2 B-operand) + bias
    short8 wf[2][6];
#pragma unroll
    for (int ot = 0; ot < 2; ++ot)
#pragma unroll
        for (int ks = 0; ks < 6; ++ks)
            wf[ot][ks] = *(const short8*)(Wpg + ((2 * wid + ot) * 16 + lam) * 192 + ks * 32 + kc);
    float bb[2];
#pragma unroll
    for (int ot = 0; ot < 2; ++ot) bb[ot] = bbg[(2 * wid + ot) * 16 + lam];

    // ---- prologue ----
    f32x2 pf2[13];
#pragma unroll
    for (int i = 0; i < 13; ++i) {
        int idx = i * 384 + tid;
        idx = idx < 4800 ? idx : 4799;
        int c = idx / 50, q2 = idx - c * 50;
        int tl = q2 >= 25, q = q2 - 25 * tl;
        pf2[i] = *(const f32x2*)(x + gb0 + c * 15000 + tl * 50 + 2 * q);
    }
    {
        const int4* src = (const int4*)bsTg;
        int4* dst = (int4*)bsT;
        for (int i = tid; i < 576; i += 384) dst[i] = src[i];
    }
    // zero xsb u-pads (both slots)
    for (int idx = tid; idx < 1344; idx += 384) {
        int r = idx / 7, k = idx - r * 7;
        int slot = r / 96, c = r - 96 * slot;
        *(unsigned int*)(xsb + ((slot * 12288 + c * 128 + (50 + 2 * k) * 2) ^ ((c & 7) << 4))) = 0;
    }
    // zero a2T pad rows 25..31 (both buffers)
    for (int idx = tid; idx < 1456; idx += 384) {
        int buf = idx / 728, rem = idx - buf * 728;
        int row = 25 + rem / 104, col2 = rem - (rem / 104) * 104;
        *((unsigned int*)&a2T[buf][row][0] + col2) = 0;
    }
    // write t0 -> slot0, t1 -> slot1
#pragma unroll
    for (int i = 0; i < 13; ++i) {
        int idx = i * 384 + tid;
        if (idx < 4800) {
            int c = idx / 50, q2 = idx - c * 50;
            int tl = q2 >= 25, q = q2 - 25 * tl;
            *(unsigned int*)(xsb + ((tl * 12288 + c * 128 + q * 4) ^ ((c & 7) << 4)))
                = pack2(pf2[i].x, pf2[i].y);
        }
    }
    asm volatile("s_waitcnt lgkmcnt(0)" ::: "memory");
    __builtin_amdgcn_s_barrier();

    const f32x4 z = {0.f, 0.f, 0.f, 0.f};
    f32x2 pf[7];
    float st[2][8];                     // banked even-t epilogue values

#pragma unroll 1
    for (int tl = 0; tl < TCF; ++tl) {
        const int slot = tl & 1;
        short* a2w = &a2T[slot][0][0];

        // issue t+2 coalesced loads early (precomputed addresses)
        if (tl < TCF - 2) {
            const float* xb2 = x + gb0 + (tl + 2) * 50;
#pragma unroll
            for (int i = 0; i < 7; ++i)
                if (i < 6 || tid < 96) pf[i] = *(const f32x2*)(xb2 + goff[i]);
        }

        // ---- GEMM1: D[v][c] (8 MFMA) ----
        short8 xb[2];
#pragma unroll
        for (int ks = 0; ks < 2; ++ks)
            xb[ks] = *(const short8*)(xsb +
                ((slot * 12288 + cgl * 128 + (ks * 32 + kc) * 2) ^ ((cgl & 7) << 4)));
        f32x4 acc1[4];
#pragma unroll
        for (int m = 0; m < 4; ++m) acc1[m] = z;
#pragma unroll
        for (int ks = 0; ks < 2; ++ks)
#pragma unroll
            for (int m = 0; m < 4; ++m) {
                const short8 af = *(const short8*)(bsT + (m * 16 + lam) * 72 + ks * 32 + kc);
                acc1[m] = __builtin_amdgcn_mfma_f32_16x16x32_bf16(af, xb[ks], acc1[m], 0, 0, 0);
            }

        // scatter agg -> a2T[slot][vs][s*96 + c]
#pragma unroll
        for (int m = 0; m < 3; ++m) {
            short4v sv = cvt4(acc1[m][0], acc1[m][1], acc1[m][2], acc1[m][3]);
#pragma unroll
            for (int r = 0; r < 4; ++r) {
                const int v = m * 16 + cb + r;
                const int s = v >= 25;
                a2w[(v - 25 * s) * 208 + s * 96 + cgl] = sv[r];
            }
        }
        if (cb == 0) {
            a2w[23 * 208 + 96 + cgl] = (short)f2bf(acc1[3][0]);
            a2w[24 * 208 + 96 + cgl] = (short)f2bf(acc1[3][1]);
        }
        asm volatile("s_waitcnt lgkmcnt(0)" ::: "memory");
        __builtin_amdgcn_s_barrier();   // a2T[slot] ready; all xb reads done

        // ---- GEMM2 (flipped): D[tv][o], W'' from registers (24 MFMA) ----
        f32x4 acc2[2][2];
#pragma unroll
        for (int g = 0; g < 2; ++g) { acc2[g][0] = z; acc2[g][1] = z; }
#pragma unroll
        for (int ks = 0; ks < 6; ++ks) {
            const short8 A0 = *(const short8*)(a2w + lam * 208 + ks * 32 + kc);
            const short8 A1 = *(const short8*)(a2w + (16 + lam) * 208 + ks * 32 + kc);
#pragma unroll
            for (int ot = 0; ot < 2; ++ot) {
                acc2[0][ot] = __builtin_amdgcn_mfma_f32_16x16x32_bf16(A0, wf[ot][ks], acc2[0][ot], 0, 0, 0);
                acc2[1][ot] = __builtin_amdgcn_mfma_f32_16x16x32_bf16(A1, wf[ot][ks], acc2[1][ot], 0, 0, 0);
            }
        }

        // ---- epilogue: defer even-t, store both t-1 and t on odd tl ----
        if ((tl & 1) == 0) {
#pragma unroll
            for (int ot = 0; ot < 2; ++ot) {
#pragma unroll
                for (int r = 0; r < 4; ++r) {
                    float vv = acc2[0][ot][r] + bb[ot];
                    st[ot][r] = vv > 0.f ? vv : 0.f;
                }
#pragma unroll
                for (int r = 0; r < 4; ++r) {
                    float vv = acc2[1][ot][r] + bb[ot];
                    st[ot][4 + r] = vv > 0.f ? vv : 0.f;
                }
            }
        } else {
            const int t = t0 + tl;
#pragma unroll
            for (int ot = 0; ot < 2; ++ot) {
                const int o = (2 * wid + ot) * 16 + lam;
                float* ope = out + ((size_t)(n * 192 + o) * 300 + (t - 1)) * 25;
                float* opo = ope + 25;
                // even-t region (banked)
#pragma unroll
                for (int r = 0; r < 4; ++r) ope[cb + r] = st[ot][r];
#pragma unroll
                for (int r = 0; r < 4; ++r) {
                    const int tv = 16 + cb + r;
                    if (tv < 25) ope[tv] = st[ot][4 + r];
                }
                // odd-t region (current)
#pragma unroll
                for (int r = 0; r < 4; ++r) {
                    float vv = acc2[0][ot][r] + bb[ot];
                    opo[cb + r] = vv > 0.f ? vv : 0.f;
                }
#pragma unroll
                for (int r = 0; r < 4; ++r) {
                    const int tv = 16 + cb + r;
                    if (tv < 25) {
                        float vv = acc2[1][ot][r] + bb[ot];
                        opo[tv] = vv > 0.f ? vv : 0.f;
                    }
                }
            }
        }

        // write t+2 into the freed slot
        if (tl < TCF - 2) {
            char* xw = xsb + slot * 12288;
#pragma unroll
            for (int i = 0; i < 7; ++i)
                if (i < 6 || tid < 96)
                    *(unsigned int*)(xw + loff[i]) = pack2(pf[i].x, pf[i].y);
        }
        // no trailing barrier: double-buffered xsb/a2T; next iter's
        // lgkm(0)+barrier orders these LDS writes before their reads.
    }
}

// ---------------------------------------------------------------------------
extern "C" void kernel_launch(void* const* d_in, const int* in_sizes, int n_in,
                              void* d_out, int out_size, void* d_ws, size_t ws_size,
                              hipStream_t stream) {
    const float* x     = (const float*)d_in[0];
    const float* xx    = (const float*)d_in[1];
    const float* A_res = (const float*)d_in[2];
    const float* W     = (const float*)d_in[3];
    const float* b     = (const float*)d_in[4];
    const float* gamma = (const float*)d_in[5];
    const float* beta  = (const float*)d_in[6];
    const float* rm    = (const float*)d_in[7];
    const float* rv    = (const float*)d_in[8];
    float* out = (float*)d_out;

    char* ws = (char*)d_ws;
    float* At_part  = (float*)ws;                    // 400000 B
    float* Acontrib = (float*)(ws + 400000);         //  80000 B
    short* bsTg     = (short*)(ws + 480000);         //   9216 B
    short* Wpg      = (short*)(ws + 489216);         //  73728 B
    float* bbg      = (float*)(ws + 562944);         //    768 B

    kA<<<dim3(5, 32), 256, 0, stream>>>(xx, At_part);
    kB1<<<32, 256, 0, stream>>>(At_part, Acontrib);
    kB2<<<37, 256, 0, stream>>>(Acontrib, A_res, W, b, gamma, beta, rm, rv, bsTg, Wpg, bbg);
    kCf<<<dim3(15, 32), 384, 0, stream>>>(x, Wpg, bsTg, bbg, out);
}